// Round 8
// baseline (1144.710 us; speedup 1.0000x reference)
//
#include <hip/hip_runtime.h>
#include <math.h>

#define UNITS 100000
#define BATCH 512
#define DIM 512
#define BN 64
#define NBLK ((UNITS + BN - 1) / BN)   /* 1563 */
#define VSTRIDE 100096                 /* vh row stride in halfs; *2B = 128-aligned */
#define SCALE 64.0f
#define COS_M2 0.87758256189037271612f /* cos(0.5) */
#define SIN_M2 0.47942553860420300027f /* sin(0.5) */
#define LOG2E  1.44269504088896340736f

typedef _Float16 half8 __attribute__((ext_vector_type(8)));
typedef _Float16 half2v __attribute__((ext_vector_type(2)));
typedef float floatx2 __attribute__((ext_vector_type(2)));
typedef float floatx4 __attribute__((ext_vector_type(4)));

// ---------------- Kernel 1: row-normalize inputs -> fragment-ordered fp16 A2 (x64) ----
__global__ void norm_emb_k(const float* __restrict__ inp, _Float16* __restrict__ A2) {
    const int row = blockIdx.x;
    const int lane = threadIdx.x;             // 64 threads = 1 wave
    const float* rp = inp + row * DIM + lane * 8;
    float v[8];
#pragma unroll
    for (int j = 0; j < 8; ++j) v[j] = rp[j];
    float ss = 0.f;
#pragma unroll
    for (int j = 0; j < 8; ++j) ss += v[j] * v[j];
#pragma unroll
    for (int off = 32; off > 0; off >>= 1) ss += __shfl_xor(ss, off);
    const float inv = SCALE / sqrtf(ss);      // fold s=64 into A
    half8 h;
#pragma unroll
    for (int j = 0; j < 8; ++j) h[j] = (_Float16)(v[j] * inv);
    const int idx = ((((row >> 4) * 16 + (lane >> 2)) * 64) + (row & 15) + 16 * (lane & 3)) * 8;
    *(half8*)(A2 + idx) = h;
}

// ---------------- Kernel 2: fused GEMM + col-norm + margin + tile-shifted exp ---------
// 512 rows x 64 cols per block, K=512 in two 32KB LDS halves; streaming loads/stores
// nontemporal so A2 stays L2-resident; 39KB LDS -> more blocks/CU.
template<bool HALF>
__global__ __launch_bounds__(512, 8) void gemm_exp_k(
    const float* __restrict__ w, const _Float16* __restrict__ A2,
    const int* __restrict__ label,
    _Float16* __restrict__ vh, float* __restrict__ outf,
    float* __restrict__ psum, float* __restrict__ pmax) {
    __shared__ _Float16 Bt[32 * 64 * 8];     // 32 KB: granule[kg][col] -> 8 k-contig halfs
    __shared__ float scratch[8][64];
    __shared__ float cninv_s[64];
    __shared__ float sums_s[512];
    __shared__ float maxs_s[512];

    const int t = threadIdx.x;
    const int blk = blockIdx.x;
    const int c0 = blk * BN;
    const int wid = t >> 6;
    const int lane = t & 63;
    const int colg = lane & 15;
    const int rowg = lane >> 4;
    const int kk = t >> 4;                   // 0..31
    const int ci = t & 15;
    const int cp = ci * 2;                   // col pair base

    bool cvj[2];
#pragma unroll
    for (int j = 0; j < 2; ++j) cvj[j] = (c0 + cp + 32 * j) < UNITS;  // pair-granular

    floatx2 va[4][2][2], vb[4][2][2];        // [i][d][j]
    auto ISSUE = [&](floatx2 (*v)[2][2], int hb) {
#pragma unroll
        for (int i = 0; i < 4; ++i)
#pragma unroll
            for (int d = 0; d < 2; ++d)
#pragma unroll
                for (int j = 0; j < 2; ++j) {
                    const size_t k = (size_t)(hb + i * 64 + kk * 2 + d);
                    const float* p = w + k * UNITS + (cvj[j] ? (c0 + cp + 32 * j) : 0);
                    v[i][d][j] = __builtin_nontemporal_load((const floatx2*)p);
                }
    };

    float sq[2][2] = {{0.f, 0.f}, {0.f, 0.f}};
    auto CONSUME = [&](floatx2 (*v)[2][2]) {
#pragma unroll
        for (int i = 0; i < 4; ++i) {
            const int kl = i * 64 + kk * 2;
            const int kg = kl >> 3;
            const int sl = kl & 7;
#pragma unroll
            for (int j = 0; j < 2; ++j)
#pragma unroll
                for (int e = 0; e < 2; ++e) {
                    float x0 = v[i][0][j][e];
                    float x1 = v[i][1][j][e];
                    if (!cvj[j]) { x0 = 0.f; x1 = 0.f; }
                    sq[j][e] += x0 * x0 + x1 * x1;
                    half2v hp; hp[0] = (_Float16)x0; hp[1] = (_Float16)x1;
                    const int col = cp + 32 * j + e;
                    *(half2v*)&Bt[(kg * 64 + col) * 8 + sl] = hp;
                }
        }
    };

    floatx4 acc[4][4];
#pragma unroll
    for (int mf = 0; mf < 4; ++mf)
#pragma unroll
        for (int nf = 0; nf < 4; ++nf) acc[mf][nf] = (floatx4){0.f, 0.f, 0.f, 0.f};

    auto MFMA_HALF = [&](int kc) {
#pragma unroll
        for (int ks = 0; ks < 8; ++ks) {
            half8 b[4];
#pragma unroll
            for (int nf = 0; nf < 4; ++nf)
                b[nf] = *(const half8*)&Bt[((ks * 4 + rowg) * 64 + nf * 16 + colg) * 8];
#pragma unroll
            for (int mf = 0; mf < 4; ++mf) {
                const half8 a = *(const half8*)(A2 +
                    (size_t)(((wid * 4 + mf) * 16 + kc * 8 + ks) * 64 + lane) * 8);
#pragma unroll
                for (int nf = 0; nf < 4; ++nf)
                    acc[mf][nf] = __builtin_amdgcn_mfma_f32_16x16x32_f16(a, b[nf], acc[mf][nf], 0, 0, 0);
            }
        }
    };

    // ---- schedule: issue all 64 loads; consume A; MFMA A (vb in flight); consume B ---
    ISSUE(va, 0);
    ISSUE(vb, 256);
    CONSUME(va);
    __syncthreads();
    MFMA_HALF(0);
    __syncthreads();
    CONSUME(vb);
    // column sq-sums: reduce over this wave's 4 k-rows, then across waves
#pragma unroll
    for (int j = 0; j < 2; ++j)
#pragma unroll
        for (int e = 0; e < 2; ++e) {
            sq[j][e] += __shfl_xor(sq[j][e], 16);
            sq[j][e] += __shfl_xor(sq[j][e], 32);
        }
    if (lane < 16) {
        scratch[wid][cp] = sq[0][0];
        scratch[wid][cp + 1] = sq[0][1];
        scratch[wid][cp + 32] = sq[1][0];
        scratch[wid][cp + 33] = sq[1][1];
    }
    __syncthreads();
    if (t < 64) {
        float s = 0.f;
#pragma unroll
        for (int g = 0; g < 8; ++g) s += scratch[g][t];
        cninv_s[t] = rsqrtf(s);
    }
    __syncthreads();
    MFMA_HALF(1);
    __syncthreads();     // all Bt reads done before bounce overwrite

    float cn[4];
#pragma unroll
    for (int nf = 0; nf < 4; ++nf) cn[nf] = cninv_s[nf * 16 + colg];

    // ---- epilogue: margin, per-(row,tile) shifted exp, padded LDS bounce, nt stores --
    _Float16* bounce = Bt + wid * 1152;      // 16 rows x 72 (padded) halfs per wave

#pragma unroll
    for (int mf = 0; mf < 4; ++mf) {
#pragma unroll
        for (int r = 0; r < 4; ++r) {
            const int Rl = wid * 64 + mf * 16 + rowg * 4 + r;
            const int labv = label[Rl];
            float lg[4];
            float mx = -1e30f;
#pragma unroll
            for (int nf = 0; nf < 4; ++nf) {
                const int C = c0 + nf * 16 + colg;
                float x = acc[mf][nf][r] * cn[nf];   // 64*cos(theta)
                if (C == labv) {
                    float cs = fminf(1.f, fmaxf(-1.f, x * (1.0f / SCALE)));
                    x = SCALE * (cs * COS_M2 - sqrtf(fmaxf(0.f, 1.f - cs * cs)) * SIN_M2);
                }
                if (C >= UNITS) x = -1e30f;
                lg[nf] = x;
                mx = fmaxf(mx, x);
            }
            mx = fmaxf(mx, __shfl_xor(mx, 1));
            mx = fmaxf(mx, __shfl_xor(mx, 2));
            mx = fmaxf(mx, __shfl_xor(mx, 4));
            mx = fmaxf(mx, __shfl_xor(mx, 8));
            float s = 0.f;
#pragma unroll
            for (int nf = 0; nf < 4; ++nf) {
                const int C = c0 + nf * 16 + colg;
                const float e = exp2f((lg[nf] - mx) * LOG2E);
                s += (C < UNITS) ? e : 0.f;
                if (HALF) bounce[(rowg * 4 + r) * 72 + nf * 16 + colg] = (_Float16)e;
                else if (C < UNITS) outf[(size_t)Rl * UNITS + C] = e;
            }
            s += __shfl_xor(s, 1);
            s += __shfl_xor(s, 2);
            s += __shfl_xor(s, 4);
            s += __shfl_xor(s, 8);
            if (colg == 0) { sums_s[Rl] = s; maxs_s[Rl] = mx; }
        }
        if (HALF) {
            // wave-local readback: 8 rows x 128B, 128-aligned rows in vh (VSTRIDE pad)
#pragma unroll
            for (int p = 0; p < 2; ++p) {
                const int row_l = p * 8 + (lane >> 3);
                const int seg = lane & 7;
                const int gc = c0 + seg * 8;
                const half8 hv = *(const half8*)&bounce[row_l * 72 + seg * 8];
                if (gc + 8 <= UNITS)
                    __builtin_nontemporal_store(hv,
                        (half8*)(vh + (size_t)(wid * 64 + mf * 16 + row_l) * VSTRIDE + gc));
            }
        }
    }

    // ---- coalesced psum/pmax block stores (2KB contiguous) ----
    __syncthreads();
    __builtin_nontemporal_store(sums_s[t], &psum[(size_t)blk * BATCH + t]);
    __builtin_nontemporal_store(maxs_s[t], &pmax[(size_t)blk * BATCH + t]);
}

// ---------------- Kernel 3: per-row global max + sum -> per-(row,tile) factor ---------
__global__ void rowfac_k(const float* __restrict__ psum, const float* __restrict__ pmax,
                         float* __restrict__ fac) {
    const int row = blockIdx.x;
    const int lane = threadIdx.x;   // 64
    float mx = -1e30f;
    for (int b = lane; b < NBLK; b += 64)
        mx = fmaxf(mx, pmax[(size_t)b * BATCH + row]);
#pragma unroll
    for (int off = 32; off > 0; off >>= 1) mx = fmaxf(mx, __shfl_xor(mx, off));
    float s = 0.f;
    for (int b = lane; b < NBLK; b += 64)
        s += psum[(size_t)b * BATCH + row] * exp2f((pmax[(size_t)b * BATCH + row] - mx) * LOG2E);
#pragma unroll
    for (int off = 32; off > 0; off >>= 1) s += __shfl_xor(s, off);
    const float invS = 1.0f / s;
    for (int b = lane; b < NBLK; b += 64)
        fac[(size_t)row * NBLK + b] = exp2f((pmax[(size_t)b * BATCH + row] - mx) * LOG2E) * invS;
}

// ---------------- Kernel 4: scale ----------------
__global__ void scale_half_k(const _Float16* __restrict__ v, const float* __restrict__ fac,
                             float* __restrict__ out) {
    const int row = blockIdx.y;
    const int c = (blockIdx.x * 256 + threadIdx.x) * 8;
    if (c >= UNITS) return;
    const float f = fac[(size_t)row * NBLK + (c >> 6)];
    const half8 h = __builtin_nontemporal_load((const half8*)(v + (size_t)row * VSTRIDE + c));
    floatx4 o1, o2;
#pragma unroll
    for (int j = 0; j < 4; ++j) { o1[j] = (float)h[j] * f; o2[j] = (float)h[4 + j] * f; }
    float* op = out + (size_t)row * UNITS + c;
    __builtin_nontemporal_store(o1, (floatx4*)op);
    __builtin_nontemporal_store(o2, (floatx4*)(op + 4));
}

__global__ void scale_f32_k(float* __restrict__ out, const float* __restrict__ fac) {
    const int row = blockIdx.y;
    const int c = (blockIdx.x * 256 + threadIdx.x) * 8;
    if (c >= UNITS) return;
    const float f = fac[(size_t)row * NBLK + (c >> 6)];
    float* op = out + (size_t)row * UNITS + c;
    floatx4 o1 = *(floatx4*)op;
    floatx4 o2 = *(floatx4*)(op + 4);
#pragma unroll
    for (int j = 0; j < 4; ++j) { o1[j] *= f; o2[j] *= f; }
    *(floatx4*)op = o1;
    *(floatx4*)(op + 4) = o2;
}

extern "C" void kernel_launch(void* const* d_in, const int* in_sizes, int n_in,
                              void* d_out, int out_size, void* d_ws, size_t ws_size,
                              hipStream_t stream) {
    const float* inp   = (const float*)d_in[0];
    const int*   label = (const int*)d_in[1];
    const float* w     = (const float*)d_in[2];
    float* out = (float*)d_out;

    char* ws = (char*)d_ws;
    _Float16* A2 = (_Float16*)ws;                 // 512 KB
    float* psum  = (float*)(ws + (4u << 20));     // 3.2 MB
    float* pmax  = (float*)(ws + (8u << 20));     // 3.2 MB
    float* fac   = (float*)(ws + (12u << 20));    // 3.2 MB
    _Float16* vh = (_Float16*)(ws + (16u << 20)); // 512*100096*2 = 102.5 MB
    const size_t need = (size_t)(16u << 20) + (size_t)BATCH * VSTRIDE * 2;
    const bool half_path = ws_size >= need;

    norm_emb_k<<<BATCH, 64, 0, stream>>>(inp, A2);
    if (half_path)
        gemm_exp_k<true><<<NBLK, 512, 0, stream>>>(w, A2, label, vh, out, psum, pmax);
    else
        gemm_exp_k<false><<<NBLK, 512, 0, stream>>>(w, A2, label, vh, out, psum, pmax);
    rowfac_k<<<BATCH, 64, 0, stream>>>(psum, pmax, fac);
    dim3 sg((UNITS + 2047) / 2048, BATCH);
    if (half_path)
        scale_half_k<<<sg, 256, 0, stream>>>(vh, fac, out);
    else
        scale_f32_k<<<sg, 256, 0, stream>>>(out, fac);
}

// Round 9
// 315.274 us; speedup vs baseline: 3.6308x; 3.6308x over previous
//
#include <hip/hip_runtime.h>
#include <math.h>

#define UNITS 100000
#define BATCH 512
#define DIM 512
#define BN 32
#define NBLK (UNITS / BN)              /* 3125 exact, no tail */
#define VSTRIDE 100096                 /* vh row stride (halfs); *2B divisible by 64 */
#define RCH 32                         /* reduction chunks */
#define CPC ((NBLK + RCH - 1) / RCH)   /* 98 tiles per chunk */
#define SCALE 64.0f
#define COS_M2 0.87758256189037271612f /* cos(0.5) */
#define SIN_M2 0.47942553860420300027f /* sin(0.5) */
#define LOG2E  1.44269504088896340736f

typedef _Float16 half8 __attribute__((ext_vector_type(8)));
typedef float floatx2 __attribute__((ext_vector_type(2)));
typedef float floatx4 __attribute__((ext_vector_type(4)));

// ---------------- Kernel 1: row-normalize inputs -> fragment-ordered fp16 A2 (x64) ----
__global__ void norm_emb_k(const float* __restrict__ inp, _Float16* __restrict__ A2) {
    const int row = blockIdx.x;
    const int lane = threadIdx.x;             // 64 threads = 1 wave
    const float* rp = inp + row * DIM + lane * 8;
    float v[8];
#pragma unroll
    for (int j = 0; j < 8; ++j) v[j] = rp[j];
    float ss = 0.f;
#pragma unroll
    for (int j = 0; j < 8; ++j) ss += v[j] * v[j];
#pragma unroll
    for (int off = 32; off > 0; off >>= 1) ss += __shfl_xor(ss, off);
    const float inv = SCALE / sqrtf(ss);      // fold s=64 into A
    half8 h;
#pragma unroll
    for (int j = 0; j < 8; ++j) h[j] = (_Float16)(v[j] * inv);
    const int idx = ((((row >> 4) * 16 + (lane >> 2)) * 64) + (row & 15) + 16 * (lane & 3)) * 8;
    *(half8*)(A2 + idx) = h;
}

// ---------------- Kernel 2: fused GEMM + col-norm + margin + tile-shifted exp ---------
// 256 threads (4 waves), tile = 256 rows (M-half) x 32 cols, K=512 in two 16KB halves.
// acc[4][2]=32 regs -> (256,5): 5 blocks/CU, no spill. M-pair blocks share XCD for L2.
template<bool HALF>
__global__ __launch_bounds__(256, 5) void gemm_exp_k(
    const float* __restrict__ w, const _Float16* __restrict__ A2,
    const int* __restrict__ label,
    _Float16* __restrict__ vh, float* __restrict__ outf,
    float* __restrict__ psum, float* __restrict__ pmax) {
    __shared__ _Float16 Bt[32 * 32 * 8];     // 16 KB: granule [kg][col] -> 8 k-contig halfs
    __shared__ float scratch[16][32];
    __shared__ float cninv_s[32];
    __shared__ float sums_s[256];
    __shared__ float maxs_s[256];

    const int t = threadIdx.x;
    const int g = blockIdx.x;
    const int ctile = (g >> 4) * 8 + (g & 7);   // pairs (mh=0/1) sit 8 apart -> same XCD
    const int mh = (g >> 3) & 1;
    if (ctile >= NBLK) return;
    const int c0 = ctile * BN;
    const int wid = t >> 6;
    const int lane = t & 63;
    const int colg = lane & 15;
    const int rowg = lane >> 4;
    const int kk = t >> 4;                   // 0..15
    const int ci = t & 15;

    const float* wp = w + (size_t)kk * UNITS + c0 + 2 * ci;
    float sq0 = 0.f, sq1 = 0.f;

    auto ISSUE = [&](floatx2* d, int qi) {   // quarter qi: k = qi*64 + s*16 + kk
#pragma unroll
        for (int s = 0; s < 4; ++s)
            d[s] = *(const floatx2*)(wp + (size_t)(qi * 64 + s * 16) * UNITS);
    };
    auto CONS = [&](const floatx2* d, int qi) {
#pragma unroll
        for (int s = 0; s < 4; ++s) {
            const int kl = (qi & 3) * 64 + s * 16 + kk;   // local k in half (0..255)
            const float x0 = d[s][0], x1 = d[s][1];
            sq0 += x0 * x0;
            sq1 += x1 * x1;
            Bt[((kl >> 3) * 32 + 2 * ci) * 8 + (kl & 7)] = (_Float16)x0;
            Bt[((kl >> 3) * 32 + 2 * ci + 1) * 8 + (kl & 7)] = (_Float16)x1;
        }
    };

    floatx4 acc[4][2];
#pragma unroll
    for (int mf = 0; mf < 4; ++mf) {
        acc[mf][0] = (floatx4){0.f, 0.f, 0.f, 0.f};
        acc[mf][1] = (floatx4){0.f, 0.f, 0.f, 0.f};
    }

    auto MFMA_HALF = [&](int h) {
#pragma unroll
        for (int ks = 0; ks < 8; ++ks) {
            const half8 b0 = *(const half8*)&Bt[((ks * 4 + rowg) * 32 + colg) * 8];
            const half8 b1 = *(const half8*)&Bt[((ks * 4 + rowg) * 32 + 16 + colg) * 8];
#pragma unroll
            for (int mf = 0; mf < 4; ++mf) {
                const int rt = mh * 16 + wid * 4 + mf;
                const half8 a = *(const half8*)(A2 +
                    (size_t)(((rt * 16) + h * 8 + ks) * 64 + lane) * 8);
                acc[mf][0] = __builtin_amdgcn_mfma_f32_16x16x32_f16(a, b0, acc[mf][0], 0, 0, 0);
                acc[mf][1] = __builtin_amdgcn_mfma_f32_16x16x32_f16(a, b1, acc[mf][1], 0, 0, 0);
            }
        }
    };

    // ---- staging/compute schedule: half-2 loads fly during half-1 MFMA ----
    floatx2 qa[4], qb[4];
    ISSUE(qa, 0); ISSUE(qb, 1);
    CONS(qa, 0);  ISSUE(qa, 2);
    CONS(qb, 1);  ISSUE(qb, 3);
    CONS(qa, 2);  CONS(qb, 3);
    ISSUE(qa, 4); ISSUE(qb, 5);          // prefetch half 2
    __syncthreads();
    MFMA_HALF(0);
    __syncthreads();
    CONS(qa, 4);  ISSUE(qa, 6);
    CONS(qb, 5);  ISSUE(qb, 7);
    CONS(qa, 6);  CONS(qb, 7);
    __syncthreads();
    MFMA_HALF(1);
    __syncthreads();

    // ---- column inv-norms ----
    scratch[kk][2 * ci] = sq0;
    scratch[kk][2 * ci + 1] = sq1;
    __syncthreads();
    if (t < 32) {
        float s = 0.f;
#pragma unroll
        for (int g2 = 0; g2 < 16; ++g2) s += scratch[g2][t];
        cninv_s[t] = rsqrtf(s);
    }
    __syncthreads();
    const float cn0 = cninv_s[colg];
    const float cn1 = cninv_s[16 + colg];

    // ---- epilogue: margin, per-(row,tile) shifted exp, wave-local bounce, stores ----
    _Float16* bounce = Bt + wid * 2048;      // 64 rows x 32 cols fp16 per wave

#pragma unroll
    for (int mf = 0; mf < 4; ++mf) {
#pragma unroll
        for (int r = 0; r < 4; ++r) {
            const int lr = mf * 16 + rowg * 4 + r;   // 0..63 within wave
            const int Rl = wid * 64 + lr;            // 0..255 within block
            const int Rg = mh * 256 + Rl;
            const int labv = label[Rg];
            float x0 = acc[mf][0][r] * cn0;
            float x1 = acc[mf][1][r] * cn1;
            const int C0 = c0 + colg, C1 = c0 + 16 + colg;
            if (C0 == labv) {
                float cs = fminf(1.f, fmaxf(-1.f, x0 * (1.0f / SCALE)));
                x0 = SCALE * (cs * COS_M2 - sqrtf(fmaxf(0.f, 1.f - cs * cs)) * SIN_M2);
            }
            if (C1 == labv) {
                float cs = fminf(1.f, fmaxf(-1.f, x1 * (1.0f / SCALE)));
                x1 = SCALE * (cs * COS_M2 - sqrtf(fmaxf(0.f, 1.f - cs * cs)) * SIN_M2);
            }
            float mx = fmaxf(x0, x1);
            mx = fmaxf(mx, __shfl_xor(mx, 1));
            mx = fmaxf(mx, __shfl_xor(mx, 2));
            mx = fmaxf(mx, __shfl_xor(mx, 4));
            mx = fmaxf(mx, __shfl_xor(mx, 8));
            const float e0 = exp2f((x0 - mx) * LOG2E);
            const float e1 = exp2f((x1 - mx) * LOG2E);
            float s = e0 + e1;
            s += __shfl_xor(s, 1);
            s += __shfl_xor(s, 2);
            s += __shfl_xor(s, 4);
            s += __shfl_xor(s, 8);
            if (HALF) {
                bounce[lr * 32 + colg] = (_Float16)e0;
                bounce[lr * 32 + 16 + colg] = (_Float16)e1;
            } else {
                outf[(size_t)Rg * UNITS + C0] = e0;
                outf[(size_t)Rg * UNITS + C1] = e1;
            }
            if (colg == 0) { sums_s[Rl] = s; maxs_s[Rl] = mx; }
        }
    }
    if (HALF) {
        // wave-local readback (DS in-order per wave): 16 rows x 64B per iteration
#pragma unroll
        for (int p = 0; p < 4; ++p) {
            const int row_l = p * 16 + (lane >> 2);
            const int seg = lane & 3;
            const half8 hv = *(const half8*)&bounce[row_l * 32 + seg * 8];
            *(half8*)(vh + (size_t)(mh * 256 + wid * 64 + row_l) * VSTRIDE + c0 + seg * 8) = hv;
        }
    }

    // ---- contiguous psum/pmax block stores (1KB each) ----
    __syncthreads();
    const size_t tb = (size_t)(ctile * 2 + mh);
    psum[tb * 256 + t] = sums_s[t];
    pmax[tb * 256 + t] = maxs_s[t];
}

// ---------------- Kernel 3: chunked online (max,sum) reduce, coalesced ----------------
__global__ void red1_k(const float* __restrict__ psum, const float* __restrict__ pmax,
                       float* __restrict__ mpart, float* __restrict__ spart) {
    const int ch = blockIdx.x;
    const int t = threadIdx.x;       // 512: mh = t>>8, rl = t&255
    const int mh = t >> 8, rl = t & 255;
    const int ct0 = ch * CPC;
    const int ct1 = (ct0 + CPC < NBLK) ? ct0 + CPC : NBLK;
    float m = -1e30f, s = 0.f;
    for (int ct = ct0; ct < ct1; ++ct) {
        const size_t idx = (size_t)(ct * 2 + mh) * 256 + rl;
        const float pm = pmax[idx];
        const float ps = psum[idx];
        if (pm > m) { s = s * exp2f((m - pm) * LOG2E) + ps; m = pm; }
        else        { s += ps * exp2f((pm - m) * LOG2E); }
    }
    mpart[ch * 512 + t] = m;
    spart[ch * 512 + t] = s;
}

// ---------------- Kernel 4: final per-row M, 1/S ----------------
__global__ void red2_k(const float* __restrict__ mpart, const float* __restrict__ spart,
                       float* __restrict__ srow) {
    const int t = threadIdx.x;       // 512
    float m = -1e30f;
#pragma unroll 4
    for (int ch = 0; ch < RCH; ++ch) m = fmaxf(m, mpart[ch * 512 + t]);
    float s = 0.f;
#pragma unroll 4
    for (int ch = 0; ch < RCH; ++ch)
        s += spart[ch * 512 + t] * exp2f((mpart[ch * 512 + t] - m) * LOG2E);
    srow[t * 2] = m;
    srow[t * 2 + 1] = 1.0f / s;
}

// ---------------- Kernel 5: scale (factor recomputed from pmax; no fac buffer) --------
__global__ void scale_half_k(const _Float16* __restrict__ vh, const float* __restrict__ pmax,
                             const float* __restrict__ srow, float* __restrict__ out) {
    const int row = blockIdx.y;
    const int c = (blockIdx.x * 256 + threadIdx.x) * 8;
    if (c >= UNITS) return;
    const int mh = row >> 8, rl = row & 255;
    const int ct = c >> 5;
    const float M = srow[row * 2];
    const float invS = srow[row * 2 + 1];
    const float pm = pmax[(size_t)(ct * 2 + mh) * 256 + rl];
    const float f = exp2f((pm - M) * LOG2E) * invS;
    const half8 h = __builtin_nontemporal_load((const half8*)(vh + (size_t)row * VSTRIDE + c));
    floatx4 o1, o2;
#pragma unroll
    for (int j = 0; j < 4; ++j) { o1[j] = (float)h[j] * f; o2[j] = (float)h[4 + j] * f; }
    float* op = out + (size_t)row * UNITS + c;
    __builtin_nontemporal_store(o1, (floatx4*)op);
    __builtin_nontemporal_store(o2, (floatx4*)(op + 4));
}

__global__ void scale_f32_k(float* __restrict__ out, const float* __restrict__ pmax,
                            const float* __restrict__ srow) {
    const int row = blockIdx.y;
    const int c = (blockIdx.x * 256 + threadIdx.x) * 8;
    if (c >= UNITS) return;
    const int mh = row >> 8, rl = row & 255;
    const int ct = c >> 5;
    const float M = srow[row * 2];
    const float invS = srow[row * 2 + 1];
    const float pm = pmax[(size_t)(ct * 2 + mh) * 256 + rl];
    const float f = exp2f((pm - M) * LOG2E) * invS;
    float* op = out + (size_t)row * UNITS + c;
    floatx4 o1 = *(floatx4*)op;
    floatx4 o2 = *(floatx4*)(op + 4);
#pragma unroll
    for (int j = 0; j < 4; ++j) { o1[j] *= f; o2[j] *= f; }
    *(floatx4*)op = o1;
    *(floatx4*)(op + 4) = o2;
}

extern "C" void kernel_launch(void* const* d_in, const int* in_sizes, int n_in,
                              void* d_out, int out_size, void* d_ws, size_t ws_size,
                              hipStream_t stream) {
    const float* inp   = (const float*)d_in[0];
    const int*   label = (const int*)d_in[1];
    const float* w     = (const float*)d_in[2];
    float* out = (float*)d_out;

    char* ws = (char*)d_ws;
    _Float16* A2 = (_Float16*)ws;                  // 512 KB
    float* psum  = (float*)(ws + (1u << 20));      // 6250*256*4 = 6.4 MB
    float* pmax  = (float*)(ws + (8u << 20));      // 6.4 MB
    float* mpart = (float*)(ws + (15u << 20));     // 64 KB
    float* spart = (float*)(ws + (15u << 20) + (1u << 17));
    float* srow  = (float*)(ws + (15u << 20) + (1u << 18));
    _Float16* vh = (_Float16*)(ws + (16u << 20));  // 512*100096*2 = 102.5 MB
    const size_t need = (size_t)(16u << 20) + (size_t)BATCH * VSTRIDE * 2;
    const bool half_path = ws_size >= need;

    const int ngrid = 391 * 16;   // covers (ctile, mh) with pair-on-XCD mapping + guard

    norm_emb_k<<<BATCH, 64, 0, stream>>>(inp, A2);
    if (half_path)
        gemm_exp_k<true><<<ngrid, 256, 0, stream>>>(w, A2, label, vh, out, psum, pmax);
    else
        gemm_exp_k<false><<<ngrid, 256, 0, stream>>>(w, A2, label, vh, out, psum, pmax);
    red1_k<<<RCH, 512, 0, stream>>>(psum, pmax, mpart, spart);
    red2_k<<<1, 512, 0, stream>>>(mpart, spart, srow);
    dim3 sg((UNITS / 8 + 255) / 256, BATCH);
    if (half_path)
        scale_half_k<<<sg, 256, 0, stream>>>(vh, pmax, srow, out);
    else
        scale_f32_k<<<sg, 256, 0, stream>>>(out, pmax, srow);
}

// Round 10
// 250.782 us; speedup vs baseline: 4.5646x; 1.2572x over previous
//
#include <hip/hip_runtime.h>
#include <math.h>

#define UNITS 100000
#define BATCH 512
#define DIM 512
#define BN 64
#define NBLK ((UNITS + BN - 1) / BN)   /* 1563 */
#define VSTRIDE 100096                 /* vh row stride in halfs; *2B = 128B-aligned */
#define SCALE 64.0f
#define COS_M2 0.87758256189037271612f /* cos(0.5) */
#define SIN_M2 0.47942553860420300027f /* sin(0.5) */
#define LOG2E  1.44269504088896340736f

typedef _Float16 half8 __attribute__((ext_vector_type(8)));
typedef float floatx4 __attribute__((ext_vector_type(4)));

// ---------------- Kernel 1: row-normalize inputs -> fragment-ordered fp16 A2 (x64) ----
__global__ void norm_emb_k(const float* __restrict__ inp, _Float16* __restrict__ A2) {
    const int row = blockIdx.x;
    const int lane = threadIdx.x;             // 64 threads = 1 wave
    const float* rp = inp + row * DIM + lane * 8;
    float v[8];
#pragma unroll
    for (int j = 0; j < 8; ++j) v[j] = rp[j];
    float ss = 0.f;
#pragma unroll
    for (int j = 0; j < 8; ++j) ss += v[j] * v[j];
#pragma unroll
    for (int off = 32; off > 0; off >>= 1) ss += __shfl_xor(ss, off);
    const float inv = SCALE / sqrtf(ss);      // fold s=64 into A
    half8 h;
#pragma unroll
    for (int j = 0; j < 8; ++j) h[j] = (_Float16)(v[j] * inv);
    const int idx = ((((row >> 4) * 16 + (lane >> 2)) * 64) + (row & 15) + 16 * (lane & 3)) * 8;
    *(half8*)(A2 + idx) = h;
}

// ---------------- Kernel 2: fused GEMM + col-norm + margin + tile-shifted exp ---------
// R2 structure (best measured: 189us): full-K 64KB staging, barrier-free MFMA loop.
// Deltas: VSTRIDE-padded vh, contiguous psum/pmax stores, padded bounce, A-prefetch.
template<bool HALF>
__global__ __launch_bounds__(512, 4) void gemm_exp_k(
    const float* __restrict__ w, const _Float16* __restrict__ A2,
    const int* __restrict__ label,
    float* __restrict__ outf, _Float16* __restrict__ vh,
    float* __restrict__ psum, float* __restrict__ pmax) {
    __shared__ _Float16 Bt[64][64][8];   // [kgrp][col][k&7], 64KB
    __shared__ float scratch[32][68];    // padded, 8.7KB
    __shared__ float cninv_s[64];
    __shared__ float sums_s[512];
    __shared__ float maxs_s[512];

    const int t = threadIdx.x;
    const int blk = blockIdx.x;
    const int c0 = blk * BN;
    const int kk = t >> 4;               // 0..31
    const int ci = t & 15;               // col base; thread covers cols ci+16j

    bool valid[4];
#pragma unroll
    for (int j = 0; j < 4; ++j) valid[j] = (c0 + ci + 16 * j) < UNITS;

    // ---- staging: full 512-k x 64-col tile -> fp16 LDS, strided cols (bank-clean) ----
    float sq[4] = {0.f, 0.f, 0.f, 0.f};
    float va[4][4], vb[4][4];

    auto issue = [&](int g, float (*dst)[4]) {
#pragma unroll
        for (int c = 0; c < 4; ++c) {
            const float* p = w + (size_t)((g * 4 + c) * 32 + kk) * UNITS + c0 + ci;
#pragma unroll
            for (int j = 0; j < 4; ++j) dst[c][j] = valid[j] ? p[16 * j] : 0.f;
        }
    };
    auto consume = [&](int g, float (*src)[4]) {
#pragma unroll
        for (int c = 0; c < 4; ++c) {
            const int k = (g * 4 + c) * 32 + kk;
#pragma unroll
            for (int j = 0; j < 4; ++j) {
                const float x = src[c][j];
                sq[j] += x * x;
                Bt[k >> 3][ci + 16 * j][k & 7] = (_Float16)x;
            }
        }
    };
    issue(0, va);
    issue(1, vb);
    consume(0, va);
    issue(2, va);
    consume(1, vb);
    issue(3, vb);
    consume(2, va);
    consume(3, vb);

#pragma unroll
    for (int j = 0; j < 4; ++j) scratch[kk][ci + 16 * j] = sq[j];

    // ---- MFMA geometry ----
    const int wid = t >> 6;
    const int lane = t & 63;
    const int colg = lane & 15;
    const int rowg = lane >> 4;
    const int rowbase = wid * 64;

    // pre-barrier A-prefetch for ks=0 (A2 loads don't depend on the staging barrier)
    half8 ap[4];
#pragma unroll
    for (int mf = 0; mf < 4; ++mf)
        ap[mf] = *(const half8*)(A2 + ((((wid * 4 + mf) * 16) + 0) * 64 + lane) * 8);

    __syncthreads();
    if (t < 64) {
        float s = 0.f;
#pragma unroll
        for (int k2 = 0; k2 < 32; ++k2) s += scratch[k2][t];
        cninv_s[t] = 1.0f / sqrtf(s);
    }

    floatx4 acc[4][4];
#pragma unroll
    for (int mf = 0; mf < 4; ++mf)
#pragma unroll
        for (int nf = 0; nf < 4; ++nf) acc[mf][nf] = (floatx4){0.f, 0.f, 0.f, 0.f};

    // ---- barrier-free MFMA loop with depth-1 A prefetch ----
#pragma unroll 2
    for (int ks = 0; ks < 16; ++ks) {
        half8 b[4];
#pragma unroll
        for (int nf = 0; nf < 4; ++nf)
            b[nf] = *(const half8*)(&Bt[ks * 4 + rowg][nf * 16 + colg][0]);
        half8 a[4];
#pragma unroll
        for (int mf = 0; mf < 4; ++mf) a[mf] = ap[mf];
        if (ks < 15) {
#pragma unroll
            for (int mf = 0; mf < 4; ++mf)
                ap[mf] = *(const half8*)(A2 + ((((wid * 4 + mf) * 16) + ks + 1) * 64 + lane) * 8);
        }
#pragma unroll
        for (int mf = 0; mf < 4; ++mf)
#pragma unroll
            for (int nf = 0; nf < 4; ++nf)
                acc[mf][nf] = __builtin_amdgcn_mfma_f32_16x16x32_f16(a[mf], b[nf], acc[mf][nf], 0, 0, 0);
    }
    __syncthreads();   // all Bt reads done before bounce overwrite; cninv_s ready

    float cn[4];
#pragma unroll
    for (int nf = 0; nf < 4; ++nf) cn[nf] = cninv_s[nf * 16 + colg];

    // ---- epilogue: margin, per-(row,tile) max-shifted exp, padded bounce, vh stores --
    _Float16* bounce = &Bt[0][0][0] + wid * 1152;   // 16 rows x 72 halfs per wave

#pragma unroll
    for (int mf = 0; mf < 4; ++mf) {
#pragma unroll
        for (int r = 0; r < 4; ++r) {
            const int lrow = mf * 16 + rowg * 4 + r;
            const int R = rowbase + lrow;
            const int labv = label[R];
            float lg[4];
            float mx = -1e30f;
#pragma unroll
            for (int nf = 0; nf < 4; ++nf) {
                const int C = c0 + nf * 16 + colg;
                float x = acc[mf][nf][r] * cn[nf];     // 64*cos(theta)
                if (C == labv) {
                    float cs = fminf(1.f, fmaxf(-1.f, x * (1.0f / SCALE)));
                    x = SCALE * (cs * COS_M2 - sqrtf(fmaxf(0.f, 1.f - cs * cs)) * SIN_M2);
                }
                if (C >= UNITS) x = -1e30f;
                lg[nf] = x;
                mx = fmaxf(mx, x);
            }
            mx = fmaxf(mx, __shfl_xor(mx, 1));
            mx = fmaxf(mx, __shfl_xor(mx, 2));
            mx = fmaxf(mx, __shfl_xor(mx, 4));
            mx = fmaxf(mx, __shfl_xor(mx, 8));
            float s = 0.f;
#pragma unroll
            for (int nf = 0; nf < 4; ++nf) {
                const int C = c0 + nf * 16 + colg;
                const float e = exp2f((lg[nf] - mx) * LOG2E);
                s += (C < UNITS) ? e : 0.f;
                if (HALF) bounce[(rowg * 4 + r) * 72 + nf * 16 + colg] = (_Float16)e;
                else if (C < UNITS) outf[(size_t)R * UNITS + C] = e;
            }
            s += __shfl_xor(s, 1);
            s += __shfl_xor(s, 2);
            s += __shfl_xor(s, 4);
            s += __shfl_xor(s, 8);
            if (colg == 0) { sums_s[R] = s; maxs_s[R] = mx; }
        }
        if (HALF) {
            // wave-local readback (DS in-order per wave): 8 rows x 128B per iteration
#pragma unroll
            for (int p = 0; p < 2; ++p) {
                const int row_l = p * 8 + (lane >> 3);
                const int seg = lane & 7;
                const int gc = c0 + seg * 8;
                const half8 hv = *(const half8*)&bounce[row_l * 72 + seg * 8];
                if (gc + 8 <= UNITS)
                    __builtin_nontemporal_store(hv,
                        (half8*)(vh + (size_t)(rowbase + mf * 16 + row_l) * VSTRIDE + gc));
            }
        }
    }

    // ---- contiguous psum/pmax block stores (2KB each, no 4B scatter inflation) ----
    __syncthreads();
    __builtin_nontemporal_store(sums_s[t], &psum[(size_t)blk * BATCH + t]);
    __builtin_nontemporal_store(maxs_s[t], &pmax[(size_t)blk * BATCH + t]);
}

// ---------------- Kernel 3: per-row global max + sum -> per-(row,tile) factor ---------
__global__ void rowfac_k(const float* __restrict__ psum, const float* __restrict__ pmax,
                         float* __restrict__ fac) {
    const int row = blockIdx.x;
    const int lane = threadIdx.x;   // 64
    float mx = -1e30f;
    for (int b = lane; b < NBLK; b += 64)
        mx = fmaxf(mx, pmax[(size_t)b * BATCH + row]);
#pragma unroll
    for (int off = 32; off > 0; off >>= 1) mx = fmaxf(mx, __shfl_xor(mx, off));
    float s = 0.f;
    for (int b = lane; b < NBLK; b += 64)
        s += psum[(size_t)b * BATCH + row] * exp2f((pmax[(size_t)b * BATCH + row] - mx) * LOG2E);
#pragma unroll
    for (int off = 32; off > 0; off >>= 1) s += __shfl_xor(s, off);
    const float invS = 1.0f / s;
    for (int b = lane; b < NBLK; b += 64)
        fac[(size_t)row * NBLK + b] = exp2f((pmax[(size_t)b * BATCH + row] - mx) * LOG2E) * invS;
}

// ---------------- Kernel 4: scale ----------------
__global__ void scale_half_k(const _Float16* __restrict__ v, const float* __restrict__ fac,
                             float* __restrict__ out) {
    const int row = blockIdx.y;
    const int c = (blockIdx.x * 256 + threadIdx.x) * 8;
    if (c >= UNITS) return;
    const float f = fac[(size_t)row * NBLK + (c >> 6)];
    const half8 h = __builtin_nontemporal_load((const half8*)(v + (size_t)row * VSTRIDE + c));
    floatx4 o1, o2;
#pragma unroll
    for (int j = 0; j < 4; ++j) { o1[j] = (float)h[j] * f; o2[j] = (float)h[4 + j] * f; }
    float* op = out + (size_t)row * UNITS + c;
    __builtin_nontemporal_store(o1, (floatx4*)op);
    __builtin_nontemporal_store(o2, (floatx4*)(op + 4));
}

__global__ void scale_f32_k(float* __restrict__ out, const float* __restrict__ fac) {
    const int row = blockIdx.y;
    const int c = (blockIdx.x * 256 + threadIdx.x) * 8;
    if (c >= UNITS) return;
    const float f = fac[(size_t)row * NBLK + (c >> 6)];
    float* op = out + (size_t)row * UNITS + c;
    floatx4 o1 = *(floatx4*)op;
    floatx4 o2 = *(floatx4*)(op + 4);
#pragma unroll
    for (int j = 0; j < 4; ++j) { o1[j] *= f; o2[j] *= f; }
    *(floatx4*)op = o1;
    *(floatx4*)(op + 4) = o2;
}

extern "C" void kernel_launch(void* const* d_in, const int* in_sizes, int n_in,
                              void* d_out, int out_size, void* d_ws, size_t ws_size,
                              hipStream_t stream) {
    const float* inp   = (const float*)d_in[0];
    const int*   label = (const int*)d_in[1];
    const float* w     = (const float*)d_in[2];
    float* out = (float*)d_out;

    char* ws = (char*)d_ws;
    _Float16* A2 = (_Float16*)ws;                 // 512 KB
    float* psum  = (float*)(ws + (4u << 20));     // 3.2 MB
    float* pmax  = (float*)(ws + (8u << 20));     // 3.2 MB
    float* fac   = (float*)(ws + (12u << 20));    // 3.2 MB
    _Float16* vh = (_Float16*)(ws + (16u << 20)); // 512*100096*2 = 102.5 MB
    const size_t need = (size_t)(16u << 20) + (size_t)BATCH * VSTRIDE * 2;
    const bool half_path = ws_size >= need;

    norm_emb_k<<<BATCH, 64, 0, stream>>>(inp, A2);
    if (half_path)
        gemm_exp_k<true><<<NBLK, 512, 0, stream>>>(w, A2, label, out, vh, psum, pmax);
    else
        gemm_exp_k<false><<<NBLK, 512, 0, stream>>>(w, A2, label, out, vh, psum, pmax);
    rowfac_k<<<BATCH, 64, 0, stream>>>(psum, pmax, fac);
    dim3 sg((UNITS / 8 + 255) / 256, BATCH);
    if (half_path)
        scale_half_k<<<sg, 256, 0, stream>>>(vh, fac, out);
    else
        scale_f32_k<<<sg, 256, 0, stream>>>(out, fac);
}